// Round 2
// baseline (13242.163 us; speedup 1.0000x reference)
//
#include <hip/hip_runtime.h>
#include <hip/hip_bf16.h>
#include <stdint.h>

// ---------------- problem constants ----------------
#define TT 512
#define BB 256
#define HH 256
#define II 128
#define OUTD 128
#define EPSV 1e-5f

// ---------------- persistent-kernel geometry ----------------
#define NCL 16      // clusters (batch slices)
#define RPC 16      // batch rows per cluster
#define WPC 8       // workgroups per cluster (each owns 32 h-cols of all 3 gates, both layers)
#define NWAVE 6     // waves per WG: wave w -> gate gt=w>>1 (r,z,n), col-sub q=w&1 (16 cols)

typedef short bf16x8 __attribute__((ext_vector_type(8)));
typedef short s16x4  __attribute__((ext_vector_type(4)));
typedef float f32x4  __attribute__((ext_vector_type(4)));

// device-scope fences (this ROCm lacks __hip_atomic_fence; use the amdgcn builtin)
#define FENCE_REL() __builtin_amdgcn_fence(__ATOMIC_RELEASE, "agent")
#define FENCE_ACQ() __builtin_amdgcn_fence(__ATOMIC_ACQUIRE, "agent")

// ---------------- workspace layout (bytes) ----------------
#define OFF_FLAG1   0u
#define OFF_FLAG2   (OFF_FLAG1 + (unsigned)(NCL*TT*4))          // 32 KB
#define OFF_BNSUM   (OFF_FLAG2 + (unsigned)(NCL*TT*4))          // 64 KB
#define OFF_BNSQ    (OFF_BNSUM + 1024u)
#define OFF_ZERO_END (OFF_BNSQ + 1024u)                         // zeroed each launch
#define OFF_H1BUF   131072u
#define HBUF_BYTES  (4u*NCL*RPC*HH*2u)                          // 512 KB ring (depth 4)
#define OFF_H2BUF   (OFF_H1BUF + HBUF_BYTES)
#define OFF_H2SEQ   (OFF_H2BUF + HBUF_BYTES)                    // B*T*H bf16 = 64 MB
#define OFF_XBF     (OFF_H2SEQ + (unsigned)(BB)*TT*HH*2u)       // x in bf16, 32 MB
// total ~97.2 MB

__device__ __forceinline__ short f2bf(float v) {
    unsigned u = __float_as_uint(v);
    u += 0x7fffu + ((u >> 16) & 1u);     // RNE
    return (short)(u >> 16);
}
__device__ __forceinline__ float bf2f(short s) {
    return __uint_as_float(((unsigned)(unsigned short)s) << 16);
}
__device__ __forceinline__ bf16x8 ldfrag_f32(const float* __restrict__ p) {
    const float4* q = (const float4*)p;
    float4 a = q[0], b = q[1];
    bf16x8 f;
    f[0]=f2bf(a.x); f[1]=f2bf(a.y); f[2]=f2bf(a.z); f[3]=f2bf(a.w);
    f[4]=f2bf(b.x); f[5]=f2bf(b.y); f[6]=f2bf(b.z); f[7]=f2bf(b.w);
    return f;
}
__device__ __forceinline__ float clamp30(float x){ return fminf(fmaxf(x, -30.f), 30.f); }
__device__ __forceinline__ float sigm(float x){ x = clamp30(x); return 1.f/(1.f + __expf(-x)); }
__device__ __forceinline__ float tanh_f(float x){
    x = clamp30(x);
    float e = __expf(-2.f * x);
    return (1.f - e) / (1.f + e);
}

// ---------------- x fp32 -> bf16 prepack ----------------
__global__ void cvt_x(const float* __restrict__ x, short* __restrict__ xbf, int n) {
    int i = (blockIdx.x * blockDim.x + threadIdx.x) * 4;
    if (i < n) {
        float4 v = *(const float4*)(x + i);
        s16x4 o; o[0]=f2bf(v.x); o[1]=f2bf(v.y); o[2]=f2bf(v.z); o[3]=f2bf(v.w);
        *(s16x4*)(xbf + i) = o;
    }
}

// ---------------- persistent 2-layer GRU ----------------
// 128 WGs, 1 per CU (co-resident). Cluster = 8 WGs exchanging h1/h2 through L2
// with device-scope flag counters. Weights live in VGPRs (bf16 MFMA B-frags).
__launch_bounds__(NWAVE*64, 2)
__global__ void gru_persist(const short* __restrict__ xbf,
                            const float* __restrict__ wih1, const float* __restrict__ whh1,
                            const float* __restrict__ bih1, const float* __restrict__ bhh1,
                            const float* __restrict__ wih2, const float* __restrict__ whh2,
                            const float* __restrict__ bih2, const float* __restrict__ bhh2,
                            char* __restrict__ ws)
{
    const int tid  = threadIdx.x;
    const int wave = tid >> 6;
    const int lane = tid & 63;
    const int qd   = lane >> 4;
    const int ln   = lane & 15;

    // cluster members share blockIdx%8 (XCD round-robin heuristic for L2 locality)
    const int xcd  = blockIdx.x & 7;
    const int slot = blockIdx.x >> 3;
    const int half = slot >> 3;
    const int mem  = slot & 7;
    const int cl   = (half << 3) | xcd;
    const int row0 = cl * RPC;       // batch rows [row0, row0+16)
    const int col0 = mem * 32;       // h-cols     [col0, col0+32)

    const int gt = wave >> 1;        // 0=r 1=z 2=n
    const int q  = wave & 1;
    const int grow = gt*256 + col0 + q*16 + ln;   // global gate row (MFMA n index)

    unsigned* flag1 = (unsigned*)(ws + OFF_FLAG1) + cl*TT;
    unsigned* flag2 = (unsigned*)(ws + OFF_FLAG2) + cl*TT;
    float* bnsum = (float*)(ws + OFF_BNSUM);
    float* bnsq  = (float*)(ws + OFF_BNSQ);
    short* h1buf = (short*)(ws + OFF_H1BUF);
    short* h2buf = (short*)(ws + OFF_H2BUF);
    short* h2seq = (short*)(ws + OFF_H2SEQ);

    // ---- weight-stationary fragments: B[n=lane&15][k=quad*8+j] (row-major N x K) ----
    bf16x8 Wi1[4], Wh1[8], Wi2[8], Wh2[8];
    #pragma unroll
    for (int kc = 0; kc < 4; ++kc) Wi1[kc] = ldfrag_f32(wih1 + grow*II + kc*32 + qd*8);
    #pragma unroll
    for (int kc = 0; kc < 8; ++kc) Wh1[kc] = ldfrag_f32(whh1 + grow*HH + kc*32 + qd*8);
    #pragma unroll
    for (int kc = 0; kc < 8; ++kc) Wi2[kc] = ldfrag_f32(wih2 + grow*HH + kc*32 + qd*8);
    #pragma unroll
    for (int kc = 0; kc < 8; ++kc) Wh2[kc] = ldfrag_f32(whh2 + grow*HH + kc*32 + qd*8);
    const float bi1 = bih1[grow], bh1 = bhh1[grow];
    const float bi2 = bih2[grow], bh2 = bhh2[grow];

    __shared__ float ldsA[6][2][16][17];   // [nb][gi|gh][m][n] layer-1 pre-acts
    __shared__ float ldsB[6][2][16][17];   // layer-2

    f32x4 h1old = {0.f,0.f,0.f,0.f};       // carried fp32 hidden (combine waves only)
    f32x4 h2old = {0.f,0.f,0.f,0.f};
    f32x4 bs = {0.f,0.f,0.f,0.f}, bq = {0.f,0.f,0.f,0.f};

    const short* xrow = xbf + (row0 + ln) * (TT*II);

    for (int t = 0; t < TT; ++t) {
        // ================= layer 1 =================
        f32x4 agi = {bi1,bi1,bi1,bi1};
        f32x4 agh = {bh1,bh1,bh1,bh1};
        #pragma unroll
        for (int kc = 0; kc < 4; ++kc) {
            bf16x8 a = *(const bf16x8*)(xrow + t*II + kc*32 + qd*8);
            agi = __builtin_amdgcn_mfma_f32_16x16x32_bf16(a, Wi1[kc], agi, 0, 0, 0);
        }
        if (t > 0) {
            const short* hp = h1buf + ((((t-1)&3)*NCL + cl)*RPC + ln)*HH;
            #pragma unroll
            for (int kc = 0; kc < 8; ++kc) {
                bf16x8 a = *(const bf16x8*)(hp + kc*32 + qd*8);
                agh = __builtin_amdgcn_mfma_f32_16x16x32_bf16(a, Wh1[kc], agh, 0, 0, 0);
            }
        }
        #pragma unroll
        for (int r = 0; r < 4; ++r) {
            ldsA[wave][0][qd*4+r][ln] = agi[r];
            ldsA[wave][1][qd*4+r][ln] = agh[r];
        }
        __syncthreads();                                  // bar1
        if (wave < 2) {                                   // combine waves: q = wave
            short* hw = h1buf + (((t&3)*NCL + cl)*RPC)*HH + col0 + wave*16 + ln;
            #pragma unroll
            for (int r = 0; r < 4; ++r) {
                int m = qd*4 + r;
                float rp  = ldsA[0+wave][0][m][ln] + ldsA[0+wave][1][m][ln];
                float zp  = ldsA[2+wave][0][m][ln] + ldsA[2+wave][1][m][ln];
                float gin = ldsA[4+wave][0][m][ln];
                float ghn = ldsA[4+wave][1][m][ln];
                float rg = sigm(rp), zg = sigm(zp);
                float ng = tanh_f(gin + rg*ghn);
                float hn = (1.f - zg)*ng + zg*h1old[r];
                h1old[r] = hn;
                hw[m*HH] = f2bf(hn);
            }
            FENCE_REL();
            if (lane == 0)
                __hip_atomic_fetch_add(&flag1[t], 1u, __ATOMIC_RELAXED, __HIP_MEMORY_SCOPE_AGENT);
        }
        // wait for full h1(t) across the cluster
        while (__hip_atomic_load(&flag1[t], __ATOMIC_RELAXED, __HIP_MEMORY_SCOPE_AGENT) < 2u*WPC)
            __builtin_amdgcn_s_sleep(1);
        FENCE_ACQ();

        // ================= layer 2 =================
        f32x4 cgi = {bi2,bi2,bi2,bi2};
        f32x4 cgh = {bh2,bh2,bh2,bh2};
        {
            const short* hp = h1buf + (((t&3)*NCL + cl)*RPC + ln)*HH;
            #pragma unroll
            for (int kc = 0; kc < 8; ++kc) {
                bf16x8 a = *(const bf16x8*)(hp + kc*32 + qd*8);
                cgi = __builtin_amdgcn_mfma_f32_16x16x32_bf16(a, Wi2[kc], cgi, 0, 0, 0);
            }
        }
        if (t > 0) {
            while (__hip_atomic_load(&flag2[t-1], __ATOMIC_RELAXED, __HIP_MEMORY_SCOPE_AGENT) < 2u*WPC)
                __builtin_amdgcn_s_sleep(1);
            FENCE_ACQ();
            const short* hp = h2buf + ((((t-1)&3)*NCL + cl)*RPC + ln)*HH;
            #pragma unroll
            for (int kc = 0; kc < 8; ++kc) {
                bf16x8 a = *(const bf16x8*)(hp + kc*32 + qd*8);
                cgh = __builtin_amdgcn_mfma_f32_16x16x32_bf16(a, Wh2[kc], cgh, 0, 0, 0);
            }
        }
        #pragma unroll
        for (int r = 0; r < 4; ++r) {
            ldsB[wave][0][qd*4+r][ln] = cgi[r];
            ldsB[wave][1][qd*4+r][ln] = cgh[r];
        }
        __syncthreads();                                  // bar2
        if (wave < 2) {
            short* hw = h2buf + (((t&3)*NCL + cl)*RPC)*HH + col0 + wave*16 + ln;
            const int colg = col0 + wave*16 + ln;
            #pragma unroll
            for (int r = 0; r < 4; ++r) {
                int m = qd*4 + r;
                float rp  = ldsB[0+wave][0][m][ln] + ldsB[0+wave][1][m][ln];
                float zp  = ldsB[2+wave][0][m][ln] + ldsB[2+wave][1][m][ln];
                float gin = ldsB[4+wave][0][m][ln];
                float ghn = ldsB[4+wave][1][m][ln];
                float rg = sigm(rp), zg = sigm(zp);
                float ng = tanh_f(gin + rg*ghn);
                float hn = (1.f - zg)*ng + zg*h2old[r];
                h2old[r] = hn;
                short hb = f2bf(hn);
                hw[m*HH] = hb;
                h2seq[((size_t)(row0+m)*TT + t)*HH + colg] = hb;
                bs[r] += hn; bq[r] += hn*hn;
            }
            FENCE_REL();
            if (lane == 0)
                __hip_atomic_fetch_add(&flag2[t], 1u, __ATOMIC_RELAXED, __HIP_MEMORY_SCOPE_AGENT);
        }
    }
    // BN batch statistics (biased): partials per (col) over this cluster's 16 rows x 512 t
    if (wave < 2) {
        const int colg = col0 + wave*16 + ln;
        atomicAdd(&bnsum[colg], bs[0]+bs[1]+bs[2]+bs[3]);
        atomicAdd(&bnsq[colg],  bq[0]+bq[1]+bq[2]+bq[3]);
    }
}

// ---------------- BN finalize + hardtanh + temporal mean + FC ----------------
__global__ void gru_final(const char* __restrict__ ws,
                          const float* __restrict__ gamma, const float* __restrict__ beta,
                          const float* __restrict__ fcw, const float* __restrict__ fcb,
                          float* __restrict__ out)
{
    __shared__ float summ[HH];
    const int b = blockIdx.x, c = threadIdx.x;
    const float* bnsum = (const float*)(ws + OFF_BNSUM);
    const float* bnsq  = (const float*)(ws + OFF_BNSQ);
    const short* h2seq = (const short*)(ws + OFF_H2SEQ);

    const float inv = 1.f / (float)(BB * TT);
    float mean = bnsum[c] * inv;
    float var  = bnsq[c] * inv - mean * mean;
    float scale = rsqrtf(var + EPSV) * gamma[c];
    float shift = beta[c] - mean * scale;

    const short* p = h2seq + (size_t)b*TT*HH + c;
    float acc = 0.f;
    #pragma unroll 4
    for (int t = 0; t < TT; ++t) {
        float v = bf2f(p[t*HH]) * scale + shift;
        v = fminf(fmaxf(v, -2.f), 2.f);
        acc += v;
    }
    summ[c] = acc * (1.f / TT);
    __syncthreads();
    if (c < OUTD) {
        float d = fcb[c];
        const float* wr = fcw + c*HH;
        #pragma unroll 8
        for (int h = 0; h < HH; ++h) d += wr[h] * summ[h];
        out[b*OUTD + c] = d;
    }
}

extern "C" void kernel_launch(void* const* d_in, const int* in_sizes, int n_in,
                              void* d_out, int out_size, void* d_ws, size_t ws_size,
                              hipStream_t stream)
{
    const float* x    = (const float*)d_in[0];
    const float* wih1 = (const float*)d_in[1];
    const float* whh1 = (const float*)d_in[2];
    const float* bih1 = (const float*)d_in[3];
    const float* bhh1 = (const float*)d_in[4];
    const float* wih2 = (const float*)d_in[5];
    const float* whh2 = (const float*)d_in[6];
    const float* bih2 = (const float*)d_in[7];
    const float* bhh2 = (const float*)d_in[8];
    const float* gamma= (const float*)d_in[9];
    const float* beta = (const float*)d_in[10];
    const float* fcw  = (const float*)d_in[11];
    const float* fcb  = (const float*)d_in[12];
    char* ws = (char*)d_ws;

    // flags + BN stat accumulators must start at 0 every launch (ws is poisoned)
    (void)hipMemsetAsync(ws, 0, OFF_ZERO_END, stream);

    // x -> bf16 prepack
    const int nx = BB*TT*II;
    hipLaunchKernelGGL(cvt_x, dim3(nx/4/256), dim3(256), 0, stream,
                       x, (short*)(ws + OFF_XBF), nx);

    // persistent recurrent kernel: 128 WGs (<= 256 CUs, all co-resident)
    hipLaunchKernelGGL(gru_persist, dim3(NCL*WPC), dim3(NWAVE*64), 0, stream,
                       (const short*)(ws + OFF_XBF),
                       wih1, whh1, bih1, bhh1, wih2, whh2, bih2, bhh2, ws);

    // epilogue
    hipLaunchKernelGGL(gru_final, dim3(BB), dim3(HH), 0, stream,
                       (const char*)ws, gamma, beta, fcw, fcb, (float*)d_out);
}

// Round 3
// 6116.706 us; speedup vs baseline: 2.1649x; 2.1649x over previous
//
#include <hip/hip_runtime.h>
#include <hip/hip_bf16.h>
#include <stdint.h>

// ---------------- problem constants ----------------
#define TT 512
#define BB 256
#define HH 256
#define II 128
#define OUTD 128
#define EPSV 1e-5f

// ---------------- persistent-kernel geometry ----------------
#define NCL 16      // clusters (batch slices)
#define RPC 16      // batch rows per cluster
#define WPC 8       // workgroups per cluster (each owns 32 h-cols of all 3 gates, both layers)
#define NWAVE 6     // waves per WG: wave w -> gate gt=w>>1 (r,z,n), col-sub q=w&1 (16 cols)

typedef short bf16x8 __attribute__((ext_vector_type(8)));
typedef short s16x4  __attribute__((ext_vector_type(4)));
typedef float f32x4  __attribute__((ext_vector_type(4)));
typedef unsigned long long u64;

// ---------------- workspace layout (bytes) ----------------
#define OFF_FLAG1   0u
#define OFF_FLAG2   (OFF_FLAG1 + (unsigned)(NCL*TT*4))          // 32 KB
#define OFF_BNSUM   (OFF_FLAG2 + (unsigned)(NCL*TT*4))          // 64 KB
#define OFF_BNSQ    (OFF_BNSUM + 1024u)
#define OFF_ZERO_END (OFF_BNSQ + 1024u)                         // zeroed each launch
#define OFF_H1BUF   131072u
#define HBUF_BYTES  (4u*NCL*RPC*HH*2u)                          // 512 KB ring (depth 4)
#define OFF_H2BUF   (OFF_H1BUF + HBUF_BYTES)
#define OFF_H2SEQ   (OFF_H2BUF + HBUF_BYTES)                    // B*T*H bf16 = 64 MB
#define OFF_XBF     (OFF_H2SEQ + (unsigned)(BB)*TT*HH*2u)       // x in bf16, 32 MB
// total ~97.2 MB

__device__ __forceinline__ short f2bf(float v) {
    unsigned u = __float_as_uint(v);
    u += 0x7fffu + ((u >> 16) & 1u);     // RNE
    return (short)(u >> 16);
}
__device__ __forceinline__ float bf2f(short s) {
    return __uint_as_float(((unsigned)(unsigned short)s) << 16);
}
__device__ __forceinline__ bf16x8 ldfrag_f32(const float* __restrict__ p) {
    const float4* q = (const float4*)p;
    float4 a = q[0], b = q[1];
    bf16x8 f;
    f[0]=f2bf(a.x); f[1]=f2bf(a.y); f[2]=f2bf(a.z); f[3]=f2bf(a.w);
    f[4]=f2bf(b.x); f[5]=f2bf(b.y); f[6]=f2bf(b.z); f[7]=f2bf(b.w);
    return f;
}
__device__ __forceinline__ float clamp30(float x){ return fminf(fmaxf(x, -30.f), 30.f); }
__device__ __forceinline__ float sigm(float x){ x = clamp30(x); return 1.f/(1.f + __expf(-x)); }
__device__ __forceinline__ float tanh_f(float x){
    x = clamp30(x);
    float e = __expf(-2.f * x);
    return (1.f - e) / (1.f + e);
}
__device__ __forceinline__ u64 pack4bf(float a, float b, float c, float d) {
    u64 r = (u64)(unsigned short)f2bf(a);
    r |= (u64)(unsigned short)f2bf(b) << 16;
    r |= (u64)(unsigned short)f2bf(c) << 32;
    r |= (u64)(unsigned short)f2bf(d) << 48;
    return r;
}
// coherent (cache-bypassing) 16B fragment read of exchanged h-state
__device__ __forceinline__ bf16x8 ld_h_frag(const short* p) {
    union { u64 u[2]; bf16x8 v; } x;
    x.u[0] = __hip_atomic_load((const u64*)p,     __ATOMIC_RELAXED, __HIP_MEMORY_SCOPE_SYSTEM);
    x.u[1] = __hip_atomic_load((const u64*)p + 1, __ATOMIC_RELAXED, __HIP_MEMORY_SCOPE_SYSTEM);
    return x.v;
}

// ---------------- x fp32 -> bf16 prepack ----------------
__global__ void cvt_x(const float* __restrict__ x, short* __restrict__ xbf, int n) {
    int i = (blockIdx.x * blockDim.x + threadIdx.x) * 4;
    if (i < n) {
        float4 v = *(const float4*)(x + i);
        s16x4 o; o[0]=f2bf(v.x); o[1]=f2bf(v.y); o[2]=f2bf(v.z); o[3]=f2bf(v.w);
        *(s16x4*)(xbf + i) = o;
    }
}

// ---------------- persistent 2-layer GRU ----------------
// 128 WGs, 1 per CU (co-resident). Cluster = 8 WGs exchanging h1/h2 through the
// coherence point with relaxed system-scope atomics — NO agent fences
// (agent REL/ACQ fences emit buffer_wbl2/buffer_inv L2-walks: 25.8us/step in R2).
__launch_bounds__(NWAVE*64, 2)
__global__ void gru_persist(const short* __restrict__ xbf,
                            const float* __restrict__ wih1, const float* __restrict__ whh1,
                            const float* __restrict__ bih1, const float* __restrict__ bhh1,
                            const float* __restrict__ wih2, const float* __restrict__ whh2,
                            const float* __restrict__ bih2, const float* __restrict__ bhh2,
                            char* __restrict__ ws)
{
    const int tid  = threadIdx.x;
    const int wave = tid >> 6;
    const int lane = tid & 63;
    const int qd   = lane >> 4;
    const int ln   = lane & 15;

    // cluster members share blockIdx%8 (XCD round-robin heuristic for L2/MALL locality)
    const int xcd  = blockIdx.x & 7;
    const int slot = blockIdx.x >> 3;
    const int half = slot >> 3;
    const int mem  = slot & 7;
    const int cl   = (half << 3) | xcd;
    const int row0 = cl * RPC;       // batch rows [row0, row0+16)
    const int col0 = mem * 32;       // h-cols     [col0, col0+32)

    const int gt = wave >> 1;        // 0=r 1=z 2=n
    const int q  = wave & 1;
    const int grow = gt*256 + col0 + q*16 + ln;   // global gate row (MFMA n index)

    unsigned* flag1 = (unsigned*)(ws + OFF_FLAG1) + cl*TT;
    unsigned* flag2 = (unsigned*)(ws + OFF_FLAG2) + cl*TT;
    float* bnsum = (float*)(ws + OFF_BNSUM);
    float* bnsq  = (float*)(ws + OFF_BNSQ);
    short* h1buf = (short*)(ws + OFF_H1BUF);
    short* h2buf = (short*)(ws + OFF_H2BUF);
    short* h2seq = (short*)(ws + OFF_H2SEQ);

    // ---- weight-stationary fragments: B[n=lane&15][k=quad*8+j] (row-major N x K) ----
    bf16x8 Wi1[4], Wh1[8], Wi2[8], Wh2[8];
    #pragma unroll
    for (int kc = 0; kc < 4; ++kc) Wi1[kc] = ldfrag_f32(wih1 + grow*II + kc*32 + qd*8);
    #pragma unroll
    for (int kc = 0; kc < 8; ++kc) Wh1[kc] = ldfrag_f32(whh1 + grow*HH + kc*32 + qd*8);
    #pragma unroll
    for (int kc = 0; kc < 8; ++kc) Wi2[kc] = ldfrag_f32(wih2 + grow*HH + kc*32 + qd*8);
    #pragma unroll
    for (int kc = 0; kc < 8; ++kc) Wh2[kc] = ldfrag_f32(whh2 + grow*HH + kc*32 + qd*8);
    const float bi1 = bih1[grow], bh1 = bhh1[grow];
    const float bi2 = bih2[grow], bh2 = bhh2[grow];

    __shared__ float ldsA[6][2][16][17];   // [wave][gi|gh][m][n] layer-1 pre-acts
    __shared__ float ldsB[6][2][16][17];   // layer-2

    // combine-lane mapping (waves 0,1): lane owns row m = lane>>2, cols c4*4..c4*4+3
    const int cm  = lane >> 2;
    const int cc4 = lane & 3;

    f32x4 h1old = {0.f,0.f,0.f,0.f};       // carried fp32 hidden per (cm, 4 cols)
    f32x4 h2old = {0.f,0.f,0.f,0.f};
    f32x4 bs = {0.f,0.f,0.f,0.f}, bq = {0.f,0.f,0.f,0.f};

    const short* xrow = xbf + (row0 + ln) * (TT*II);

    for (int t = 0; t < TT; ++t) {
        // ================= layer 1 =================
        f32x4 agi = {bi1,bi1,bi1,bi1};
        f32x4 agh = {bh1,bh1,bh1,bh1};
        #pragma unroll
        for (int kc = 0; kc < 4; ++kc) {
            bf16x8 a = *(const bf16x8*)(xrow + t*II + kc*32 + qd*8);
            agi = __builtin_amdgcn_mfma_f32_16x16x32_bf16(a, Wi1[kc], agi, 0, 0, 0);
        }
        if (t > 0) {
            const short* hp = h1buf + ((((t-1)&3)*NCL + cl)*RPC + ln)*HH;
            #pragma unroll
            for (int kc = 0; kc < 8; ++kc) {
                bf16x8 a = ld_h_frag(hp + kc*32 + qd*8);
                agh = __builtin_amdgcn_mfma_f32_16x16x32_bf16(a, Wh1[kc], agh, 0, 0, 0);
            }
        }
        #pragma unroll
        for (int r = 0; r < 4; ++r) {
            ldsA[wave][0][qd*4+r][ln] = agi[r];
            ldsA[wave][1][qd*4+r][ln] = agh[r];
        }
        __syncthreads();                                  // bar1: ldsA complete
        if (wave < 2) {                                   // combine waves: q = wave
            f32x4 hn;
            #pragma unroll
            for (int j = 0; j < 4; ++j) {
                int c = cc4*4 + j;
                float rp  = ldsA[0+wave][0][cm][c] + ldsA[0+wave][1][cm][c];
                float zp  = ldsA[2+wave][0][cm][c] + ldsA[2+wave][1][cm][c];
                float gin = ldsA[4+wave][0][cm][c];
                float ghn = ldsA[4+wave][1][cm][c];
                float rg = sigm(rp), zg = sigm(zp);
                float ng = tanh_f(gin + rg*ghn);
                hn[j] = (1.f - zg)*ng + zg*h1old[j];
                h1old[j] = hn[j];
            }
            u64 pk = pack4bf(hn[0], hn[1], hn[2], hn[3]);
            short* hw = h1buf + (((t&3)*NCL + cl)*RPC + cm)*HH + col0 + wave*16 + cc4*4;
            __hip_atomic_store((u64*)hw, pk, __ATOMIC_RELAXED, __HIP_MEMORY_SCOPE_SYSTEM);
            asm volatile("s_waitcnt vmcnt(0)" ::: "memory");   // data at coherence point
            if (lane == 0)
                __hip_atomic_fetch_add(&flag1[t], 1u, __ATOMIC_RELAXED, __HIP_MEMORY_SCOPE_SYSTEM);
        } else if (wave == 2) {
            // single polling wave per WG (avoid 48-wave hammering of the flag line)
            while (__hip_atomic_load(&flag1[t], __ATOMIC_RELAXED, __HIP_MEMORY_SCOPE_SYSTEM) < 2u*WPC)
                __builtin_amdgcn_s_sleep(1);
        }
        __syncthreads();                                  // bar1b: h1(t) visible cluster-wide

        // ================= layer 2 =================
        f32x4 cgi = {bi2,bi2,bi2,bi2};
        f32x4 cgh = {bh2,bh2,bh2,bh2};
        {
            const short* hp = h1buf + (((t&3)*NCL + cl)*RPC + ln)*HH;
            #pragma unroll
            for (int kc = 0; kc < 8; ++kc) {
                bf16x8 a = ld_h_frag(hp + kc*32 + qd*8);
                cgi = __builtin_amdgcn_mfma_f32_16x16x32_bf16(a, Wi2[kc], cgi, 0, 0, 0);
            }
        }
        if (t > 0) {
            // usually already satisfied (posted by this cluster at step t-1)
            while (__hip_atomic_load(&flag2[t-1], __ATOMIC_RELAXED, __HIP_MEMORY_SCOPE_SYSTEM) < 2u*WPC)
                __builtin_amdgcn_s_sleep(1);
            asm volatile("" ::: "memory");
            const short* hp = h2buf + ((((t-1)&3)*NCL + cl)*RPC + ln)*HH;
            #pragma unroll
            for (int kc = 0; kc < 8; ++kc) {
                bf16x8 a = ld_h_frag(hp + kc*32 + qd*8);
                cgh = __builtin_amdgcn_mfma_f32_16x16x32_bf16(a, Wh2[kc], cgh, 0, 0, 0);
            }
        }
        #pragma unroll
        for (int r = 0; r < 4; ++r) {
            ldsB[wave][0][qd*4+r][ln] = cgi[r];
            ldsB[wave][1][qd*4+r][ln] = cgh[r];
        }
        __syncthreads();                                  // bar2: ldsB complete
        if (wave < 2) {
            f32x4 hn;
            #pragma unroll
            for (int j = 0; j < 4; ++j) {
                int c = cc4*4 + j;
                float rp  = ldsB[0+wave][0][cm][c] + ldsB[0+wave][1][cm][c];
                float zp  = ldsB[2+wave][0][cm][c] + ldsB[2+wave][1][cm][c];
                float gin = ldsB[4+wave][0][cm][c];
                float ghn = ldsB[4+wave][1][cm][c];
                float rg = sigm(rp), zg = sigm(zp);
                float ng = tanh_f(gin + rg*ghn);
                hn[j] = (1.f - zg)*ng + zg*h2old[j];
                h2old[j] = hn[j];
                bs[j] += hn[j]; bq[j] += hn[j]*hn[j];
            }
            u64 pk = pack4bf(hn[0], hn[1], hn[2], hn[3]);
            const int colg = col0 + wave*16 + cc4*4;
            short* hw = h2buf + (((t&3)*NCL + cl)*RPC + cm)*HH + colg;
            __hip_atomic_store((u64*)hw, pk, __ATOMIC_RELAXED, __HIP_MEMORY_SCOPE_SYSTEM);
            asm volatile("s_waitcnt vmcnt(0)" ::: "memory");
            if (lane == 0)
                __hip_atomic_fetch_add(&flag2[t], 1u, __ATOMIC_RELAXED, __HIP_MEMORY_SCOPE_SYSTEM);
            // sequence output AFTER the flag post: HBM ack stays off the critical path
            __builtin_nontemporal_store(pk, (u64*)(h2seq + ((size_t)(row0+cm)*TT + t)*HH + colg));
        }
        // no bar2b needed: gh1(t+1) uses h1(t) (already exchanged); gh2(t+1) polls flag2[t]
    }
    // BN batch statistics (biased): partials per col over this cluster's 16 rows x 512 t
    if (wave < 2) {
        const int colg = col0 + wave*16 + cc4*4;
        #pragma unroll
        for (int j = 0; j < 4; ++j) {
            atomicAdd(&bnsum[colg+j], bs[j]);
            atomicAdd(&bnsq[colg+j],  bq[j]);
        }
    }
}

// ---------------- BN finalize + hardtanh + temporal mean + FC ----------------
__global__ void gru_final(const char* __restrict__ ws,
                          const float* __restrict__ gamma, const float* __restrict__ beta,
                          const float* __restrict__ fcw, const float* __restrict__ fcb,
                          float* __restrict__ out)
{
    __shared__ float summ[HH];
    const int b = blockIdx.x, c = threadIdx.x;
    const float* bnsum = (const float*)(ws + OFF_BNSUM);
    const float* bnsq  = (const float*)(ws + OFF_BNSQ);
    const short* h2seq = (const short*)(ws + OFF_H2SEQ);

    const float inv = 1.f / (float)(BB * TT);
    float mean = bnsum[c] * inv;
    float var  = bnsq[c] * inv - mean * mean;
    float scale = rsqrtf(var + EPSV) * gamma[c];
    float shift = beta[c] - mean * scale;

    const short* p = h2seq + (size_t)b*TT*HH + c;
    float acc = 0.f;
    #pragma unroll 4
    for (int t = 0; t < TT; ++t) {
        float v = bf2f(p[t*HH]) * scale + shift;
        v = fminf(fmaxf(v, -2.f), 2.f);
        acc += v;
    }
    summ[c] = acc * (1.f / TT);
    __syncthreads();
    if (c < OUTD) {
        float d = fcb[c];
        const float* wr = fcw + c*HH;
        #pragma unroll 8
        for (int h = 0; h < HH; ++h) d += wr[h] * summ[h];
        out[b*OUTD + c] = d;
    }
}

extern "C" void kernel_launch(void* const* d_in, const int* in_sizes, int n_in,
                              void* d_out, int out_size, void* d_ws, size_t ws_size,
                              hipStream_t stream)
{
    const float* x    = (const float*)d_in[0];
    const float* wih1 = (const float*)d_in[1];
    const float* whh1 = (const float*)d_in[2];
    const float* bih1 = (const float*)d_in[3];
    const float* bhh1 = (const float*)d_in[4];
    const float* wih2 = (const float*)d_in[5];
    const float* whh2 = (const float*)d_in[6];
    const float* bih2 = (const float*)d_in[7];
    const float* bhh2 = (const float*)d_in[8];
    const float* gamma= (const float*)d_in[9];
    const float* beta = (const float*)d_in[10];
    const float* fcw  = (const float*)d_in[11];
    const float* fcb  = (const float*)d_in[12];
    char* ws = (char*)d_ws;

    // flags + BN stat accumulators must start at 0 every launch (ws is poisoned)
    (void)hipMemsetAsync(ws, 0, OFF_ZERO_END, stream);

    // x -> bf16 prepack
    const int nx = BB*TT*II;
    hipLaunchKernelGGL(cvt_x, dim3(nx/4/256), dim3(256), 0, stream,
                       x, (short*)(ws + OFF_XBF), nx);

    // persistent recurrent kernel: 128 WGs (<= 256 CUs, all co-resident)
    hipLaunchKernelGGL(gru_persist, dim3(NCL*WPC), dim3(NWAVE*64), 0, stream,
                       (const short*)(ws + OFF_XBF),
                       wih1, whh1, bih1, bhh1, wih2, whh2, bih2, bhh2, ws);

    // epilogue
    hipLaunchKernelGGL(gru_final, dim3(BB), dim3(HH), 0, stream,
                       (const char*)ws, gamma, beta, fcw, fcb, (float*)d_out);
}

// Round 4
// 3380.095 us; speedup vs baseline: 3.9177x; 1.8096x over previous
//
#include <hip/hip_runtime.h>
#include <hip/hip_bf16.h>
#include <stdint.h>

// ---------------- problem constants ----------------
#define TT 512
#define BB 256
#define HH 256
#define II 128
#define OUTD 128
#define EPSV 1e-5f

// ---------------- pipeline geometry ----------------
// 16 clusters x 16 batch rows. Per cluster: 4 WGs (stages) of 512 threads:
//   M1: gi1 = x@Wih1^T (+biases)  [runs ahead]   + chore (h2 ring -> h2seq + BN)
//   A : gh1 recurrence (h1 state in own LDS)     <- THE serial chain
//   M2: gi2 = h1@Wih2^T (+biases)
//   B : gh2 recurrence (h2 state in own LDS)
// All cross-WG links one-directional through 8-deep rings at system scope.
#define NCL 16
#define RPC 16
#define RD  8       // ring depth (steps)
#define CLAG 8      // chore lag on M1
#define HPAD 264    // LDS row stride (shorts); 528B => conflict-free b128 frag reads

#define ST_M1 0
#define ST_A  1
#define ST_M2 2
#define ST_B  3

typedef short bf16x8 __attribute__((ext_vector_type(8)));
typedef short s16x4  __attribute__((ext_vector_type(4)));
typedef float f32x4  __attribute__((ext_vector_type(4)));
typedef unsigned long long u64;

// ---------------- workspace layout (bytes) ----------------
#define OFF_PROG     0u                         // 16 cl x 4 stages x u32
#define OFF_BNSUM    1024u
#define OFF_BNSQ     2048u
#define OFF_ZERO_END 3072u
#define OFF_GI1      65536u
#define GI_BYTES     (NCL*RD*768u*16u*4u)       // 6.29 MB (fp32 pre-acts)
#define OFF_GI2      (OFF_GI1 + GI_BYTES)
#define OFF_H1R      (OFF_GI2 + GI_BYTES)
#define HR_BYTES     (NCL*RD*4096u*2u)          // 1 MB (bf16 h, [col][row])
#define OFF_H2R      (OFF_H1R + HR_BYTES)
#define OFF_H2SEQ    (OFF_H2R + HR_BYTES)       // 64 MB bf16 [b][t][h]
#define OFF_XBF      (OFF_H2SEQ + (unsigned)BB*TT*HH*2u)   // 32 MB
// total ~115 MB

__device__ __forceinline__ short f2bf(float v) {
    unsigned u = __float_as_uint(v);
    u += 0x7fffu + ((u >> 16) & 1u);
    return (short)(u >> 16);
}
__device__ __forceinline__ float bf2f(short s) {
    return __uint_as_float(((unsigned)(unsigned short)s) << 16);
}
__device__ __forceinline__ bf16x8 ldfrag_f32(const float* __restrict__ p) {
    const float4* q = (const float4*)p;
    float4 a = q[0], b = q[1];
    bf16x8 f;
    f[0]=f2bf(a.x); f[1]=f2bf(a.y); f[2]=f2bf(a.z); f[3]=f2bf(a.w);
    f[4]=f2bf(b.x); f[5]=f2bf(b.y); f[6]=f2bf(b.z); f[7]=f2bf(b.w);
    return f;
}
__device__ __forceinline__ float clamp30(float x){ return fminf(fmaxf(x, -30.f), 30.f); }
__device__ __forceinline__ float sigm(float x){ x = clamp30(x); return 1.f/(1.f + __expf(-x)); }
__device__ __forceinline__ float tanh_f(float x){
    x = clamp30(x);
    float e = __expf(-2.f * x);
    return (1.f - e) / (1.f + e);
}
__device__ __forceinline__ void poll_ge(const unsigned* p, int tgt) {
    if (tgt <= 0) return;
    while ((int)__hip_atomic_load((unsigned*)p, __ATOMIC_RELAXED, __HIP_MEMORY_SCOPE_SYSTEM) < tgt)
        __builtin_amdgcn_s_sleep(2);
}
__device__ __forceinline__ void post_prog(unsigned* p, int v) {
    __hip_atomic_store(p, (unsigned)v, __ATOMIC_RELAXED, __HIP_MEMORY_SCOPE_SYSTEM);
}
__device__ __forceinline__ f32x4 ld_f4_coh(const float* p) {
    union { u64 u[2]; f32x4 v; } x;
    x.u[0] = __hip_atomic_load((u64*)p,     __ATOMIC_RELAXED, __HIP_MEMORY_SCOPE_SYSTEM);
    x.u[1] = __hip_atomic_load((u64*)p + 1, __ATOMIC_RELAXED, __HIP_MEMORY_SCOPE_SYSTEM);
    return x.v;
}
__device__ __forceinline__ void st_f4_coh(float* p, f32x4 v) {
    union { u64 u[2]; f32x4 v; } x; x.v = v;
    __hip_atomic_store((u64*)p,     x.u[0], __ATOMIC_RELAXED, __HIP_MEMORY_SCOPE_SYSTEM);
    __hip_atomic_store((u64*)p + 1, x.u[1], __ATOMIC_RELAXED, __HIP_MEMORY_SCOPE_SYSTEM);
}
__device__ __forceinline__ u64 ld_u64_coh(const u64* p) {
    return __hip_atomic_load((u64*)p, __ATOMIC_RELAXED, __HIP_MEMORY_SCOPE_SYSTEM);
}
__device__ __forceinline__ void st_u64_coh(u64* p, u64 v) {
    __hip_atomic_store(p, v, __ATOMIC_RELAXED, __HIP_MEMORY_SCOPE_SYSTEM);
}

// ---------------- x fp32 -> bf16 prepack ----------------
__global__ void cvt_x(const float* __restrict__ x, short* __restrict__ xbf, int n) {
    int i = (blockIdx.x * blockDim.x + threadIdx.x) * 4;
    if (i < n) {
        float4 v = *(const float4*)(x + i);
        s16x4 o; o[0]=f2bf(v.x); o[1]=f2bf(v.y); o[2]=f2bf(v.z); o[3]=f2bf(v.w);
        *(s16x4*)(xbf + i) = o;
    }
}

// ---------------- persistent 4-stage pipeline ----------------
__global__ void __launch_bounds__(512, 2)
gru_pipe(const short* __restrict__ xbf,
         const float* __restrict__ wih1, const float* __restrict__ whh1,
         const float* __restrict__ bih1, const float* __restrict__ bhh1,
         const float* __restrict__ wih2, const float* __restrict__ whh2,
         const float* __restrict__ bih2, const float* __restrict__ bhh2,
         char* __restrict__ ws)
{
    const int tid  = threadIdx.x;
    const int wave = tid >> 6;     // 0..7
    const int lane = tid & 63;
    const int qd   = lane >> 4;    // 0..3
    const int ln   = lane & 15;

    // block decode: cluster's 4 stages land on the same XCD (i%8 heuristic)
    const int bi   = blockIdx.x;
    const int clo  = bi & 7;
    const int jj   = bi >> 3;
    const int stage= jj & 3;
    const int chi  = jj >> 2;
    const int cl   = chi * 8 + clo;
    const int grow0= cl * RPC;

    unsigned* prog = (unsigned*)(ws + OFF_PROG) + cl * 4;
    float* bnsum = (float*)(ws + OFF_BNSUM);
    float* bnsq  = (float*)(ws + OFF_BNSQ);
    short* h2seq = (short*)(ws + OFF_H2SEQ);

    __shared__ __align__(16) short hb[2][16][HPAD];

    if (stage == ST_M1) {
        // ================= M1: gi1 producer + h2 chore =================
        bf16x8 W[2][3][4];
        f32x4 cinit[2][3];
        #pragma unroll
        for (int b2 = 0; b2 < 2; ++b2)
        #pragma unroll
        for (int g = 0; g < 3; ++g) {
            const int grow = g*256 + (2*wave + b2)*16 + ln;
            #pragma unroll
            for (int kc = 0; kc < 4; ++kc)
                W[b2][g][kc] = ldfrag_f32(wih1 + grow*II + kc*32 + qd*8);
            float c0 = bih1[grow] + (g < 2 ? bhh1[grow] : 0.f);
            cinit[b2][g] = f32x4{c0, c0, c0, c0};
        }
        const short* xr = xbf + (grow0 + ln) * (TT*II);
        float* gi1ring = (float*)(ws + OFF_GI1);
        const u64* h2ring = (const u64*)(ws + OFF_H2R);
        const int ccol = tid >> 1, crow = (tid & 1) * 8;
        float cbs = 0.f, cbq = 0.f;

        for (int s = 0; s < TT + CLAG; ++s) {
            if (s < TT) {
                poll_ge(&prog[ST_A], s - 7);            // gi1 ring backpressure
                f32x4 acc[2][3];
                #pragma unroll
                for (int b2 = 0; b2 < 2; ++b2)
                #pragma unroll
                for (int g = 0; g < 3; ++g) acc[b2][g] = cinit[b2][g];
                #pragma unroll
                for (int kc = 0; kc < 4; ++kc) {
                    bf16x8 a = *(const bf16x8*)(xr + s*II + kc*32 + qd*8);
                    #pragma unroll
                    for (int b2 = 0; b2 < 2; ++b2)
                    #pragma unroll
                    for (int g = 0; g < 3; ++g)
                        acc[b2][g] = __builtin_amdgcn_mfma_f32_16x16x32_bf16(a, W[b2][g][kc], acc[b2][g], 0, 0, 0);
                }
                float* gb = gi1ring + (cl*RD + (s & 7)) * 12288;
                #pragma unroll
                for (int b2 = 0; b2 < 2; ++b2)
                #pragma unroll
                for (int g = 0; g < 3; ++g)
                    st_f4_coh(gb + ((2*wave + b2)*3 + g)*256 + ln*16 + qd*4, acc[b2][g]);
            }
            const int u = s - CLAG;
            if (u >= 0 && u < TT) {                      // chore: h2(u) -> h2seq + BN
                poll_ge(&prog[ST_B], u + 1);
                const u64* hrb = h2ring + (cl*RD + (u & 7)) * 1024;
                u64 v0 = ld_u64_coh(hrb + 2*tid);
                u64 v1 = ld_u64_coh(hrb + 2*tid + 1);
                #pragma unroll
                for (int k = 0; k < 4; ++k) {
                    short a0 = (short)(v0 >> (16*k));
                    short a1 = (short)(v1 >> (16*k));
                    h2seq[(size_t)(grow0 + crow + k    )*TT*HH + (size_t)u*HH + ccol] = a0;
                    h2seq[(size_t)(grow0 + crow + k + 4)*TT*HH + (size_t)u*HH + ccol] = a1;
                    float f0 = bf2f(a0), f1 = bf2f(a1);
                    cbs += f0 + f1; cbq += f0*f0 + f1*f1;
                }
            }
            if (s < TT) {
                asm volatile("s_waitcnt vmcnt(0)" ::: "memory");
                __syncthreads();
                if (tid == 0) post_prog(&prog[ST_M1], s + 1);
            } else {
                __syncthreads();
            }
        }
        if (tid & 1) { /* only one lane per col pair adds both? no: each lane owns distinct rows */ }
        atomicAdd(&bnsum[ccol], cbs);
        atomicAdd(&bnsq[ccol],  cbq);

    } else if (stage == ST_M2) {
        // ================= M2: gi2 = h1 @ Wih2^T =================
        bf16x8 W[2][3][8];
        f32x4 cinit[2][3];
        #pragma unroll
        for (int b2 = 0; b2 < 2; ++b2)
        #pragma unroll
        for (int g = 0; g < 3; ++g) {
            const int grow = g*256 + (2*wave + b2)*16 + ln;
            #pragma unroll
            for (int kc = 0; kc < 8; ++kc)
                W[b2][g][kc] = ldfrag_f32(wih2 + grow*HH + kc*32 + qd*8);
            float c0 = bih2[grow] + (g < 2 ? bhh2[grow] : 0.f);
            cinit[b2][g] = f32x4{c0, c0, c0, c0};
        }
        float* gi2ring = (float*)(ws + OFF_GI2);
        const u64* h1ring = (const u64*)(ws + OFF_H1R);
        const int pcol = tid >> 1, prow = (tid & 1) * 8;

        // prologue: fetch h1(0) into buf0
        poll_ge(&prog[ST_A], 1);
        {
            const u64* hrb = h1ring + (cl*RD + 0) * 1024;
            u64 v0 = ld_u64_coh(hrb + 2*tid);
            u64 v1 = ld_u64_coh(hrb + 2*tid + 1);
            #pragma unroll
            for (int k = 0; k < 4; ++k) {
                hb[0][prow + k    ][pcol] = (short)(v0 >> (16*k));
                hb[0][prow + k + 4][pcol] = (short)(v1 >> (16*k));
            }
        }
        __syncthreads();

        for (int t = 0; t < TT; ++t) {
            f32x4 acc[2][3];
            #pragma unroll
            for (int b2 = 0; b2 < 2; ++b2)
            #pragma unroll
            for (int g = 0; g < 3; ++g) acc[b2][g] = cinit[b2][g];
            const int buf = t & 1;
            #pragma unroll
            for (int kc = 0; kc < 8; ++kc) {
                bf16x8 f = *(const bf16x8*)&hb[buf][ln][kc*32 + qd*8];
                #pragma unroll
                for (int b2 = 0; b2 < 2; ++b2)
                #pragma unroll
                for (int g = 0; g < 3; ++g)
                    acc[b2][g] = __builtin_amdgcn_mfma_f32_16x16x32_bf16(f, W[b2][g][kc], acc[b2][g], 0, 0, 0);
            }
            float* gb = gi2ring + (cl*RD + (t & 7)) * 12288;
            #pragma unroll
            for (int b2 = 0; b2 < 2; ++b2)
            #pragma unroll
            for (int g = 0; g < 3; ++g)
                st_f4_coh(gb + ((2*wave + b2)*3 + g)*256 + ln*16 + qd*4, acc[b2][g]);
            // prefetch h1(t+1) into other buf
            if (t + 1 < TT) {
                poll_ge(&prog[ST_A], t + 2);
                const u64* hrb = h1ring + (cl*RD + ((t+1) & 7)) * 1024;
                u64 v0 = ld_u64_coh(hrb + 2*tid);
                u64 v1 = ld_u64_coh(hrb + 2*tid + 1);
                #pragma unroll
                for (int k = 0; k < 4; ++k) {
                    hb[1 - buf][prow + k    ][pcol] = (short)(v0 >> (16*k));
                    hb[1 - buf][prow + k + 4][pcol] = (short)(v1 >> (16*k));
                }
            }
            poll_ge(&prog[ST_B], t - 7);                 // gi2 ring backpressure
            __syncthreads();
            if (tid == 0) post_prog(&prog[ST_M2], t);    // covers gi2(t-1)
        }
        asm volatile("s_waitcnt vmcnt(0)" ::: "memory");
        __syncthreads();
        if (tid == 0) post_prog(&prog[ST_M2], TT);

    } else {
        // ================= A (gh1 recurrence) / B (gh2 recurrence) =================
        const bool isA = (stage == ST_A);
        const float* Wh  = isA ? whh1 : whh2;
        const float* bhh = isA ? bhh1 : bhh2;
        float* giring = (float*)(ws + (isA ? OFF_GI1 : OFF_GI2));
        u64*   hring  = (u64*)  (ws + (isA ? OFF_H1R : OFF_H2R));
        unsigned* availP = &prog[isA ? ST_M1 : ST_M2];
        unsigned* bpP    = &prog[isA ? ST_M2 : ST_M1];
        unsigned* myP    = &prog[isA ? ST_A  : ST_B];
        const int bpAdd  = isA ? -7 : 0;

        bf16x8 W[2][3][8];
        float bnn[2];
        #pragma unroll
        for (int b2 = 0; b2 < 2; ++b2) {
            #pragma unroll
            for (int g = 0; g < 3; ++g) {
                const int grow = g*256 + (2*wave + b2)*16 + ln;
                #pragma unroll
                for (int kc = 0; kc < 8; ++kc)
                    W[b2][g][kc] = ldfrag_f32(Wh + grow*HH + kc*32 + qd*8);
            }
            bnn[b2] = bhh[2*256 + (2*wave + b2)*16 + ln];
        }
        float hold[2][4];
        #pragma unroll
        for (int b2 = 0; b2 < 2; ++b2)
        #pragma unroll
        for (int r = 0; r < 4; ++r) hold[b2][r] = 0.f;

        // zero h(-1) state (buf0)
        {
            u64* z = (u64*)&hb[0][0][0];
            for (int i = tid; i < 16*HPAD/4; i += 512) z[i] = 0ull;
        }
        __syncthreads();

        for (int t = 0; t < TT; ++t) {
            poll_ge(availP, t + 1);                       // gi(t) available (drain-proving use)
            poll_ge(bpP, t + bpAdd);                      // h ring backpressure
            const float* gb = giring + (cl*RD + (t & 7)) * 12288;
            f32x4 aR[2], aZ[2], aN[2], gN[2];
            #pragma unroll
            for (int b2 = 0; b2 < 2; ++b2) {
                const int toff = (2*wave + b2)*3*256 + ln*16 + qd*4;
                aR[b2] = ld_f4_coh(gb + toff);
                aZ[b2] = ld_f4_coh(gb + toff + 256);
                gN[b2] = ld_f4_coh(gb + toff + 512);
                aN[b2] = f32x4{bnn[b2], bnn[b2], bnn[b2], bnn[b2]};
            }
            const int buf = t & 1;
            #pragma unroll
            for (int kc = 0; kc < 8; ++kc) {
                bf16x8 f = *(const bf16x8*)&hb[buf][ln][kc*32 + qd*8];
                aN[0] = __builtin_amdgcn_mfma_f32_16x16x32_bf16(f, W[0][2][kc], aN[0], 0, 0, 0);
                aN[1] = __builtin_amdgcn_mfma_f32_16x16x32_bf16(f, W[1][2][kc], aN[1], 0, 0, 0);
                aR[0] = __builtin_amdgcn_mfma_f32_16x16x32_bf16(f, W[0][0][kc], aR[0], 0, 0, 0);
                aR[1] = __builtin_amdgcn_mfma_f32_16x16x32_bf16(f, W[1][0][kc], aR[1], 0, 0, 0);
                aZ[0] = __builtin_amdgcn_mfma_f32_16x16x32_bf16(f, W[0][1][kc], aZ[0], 0, 0, 0);
                aZ[1] = __builtin_amdgcn_mfma_f32_16x16x32_bf16(f, W[1][1][kc], aZ[1], 0, 0, 0);
            }
            // combine + distribute
            #pragma unroll
            for (int b2 = 0; b2 < 2; ++b2) {
                const int colg = (2*wave + b2)*16 + ln;
                u64 pk = 0;
                #pragma unroll
                for (int r = 0; r < 4; ++r) {
                    float rg = sigm(aR[b2][r]);
                    float zg = sigm(aZ[b2][r]);
                    float ng = tanh_f(gN[b2][r] + rg * aN[b2][r]);
                    float h  = (1.f - zg)*ng + zg*hold[b2][r];
                    hold[b2][r] = h;
                    short hs = f2bf(h);
                    hb[1 - buf][qd*4 + r][colg] = hs;
                    pk |= (u64)(unsigned short)hs << (16*r);
                }
                st_u64_coh(hring + (cl*RD + (t & 7))*1024 + colg*4 + qd, pk);
            }
            __syncthreads();
            if (tid == 0) post_prog(myP, t);              // covers h(t-1)
        }
        asm volatile("s_waitcnt vmcnt(0)" ::: "memory");
        __syncthreads();
        if (tid == 0) post_prog(myP, TT);
    }
}

// ---------------- BN finalize + hardtanh + temporal mean + FC ----------------
__global__ void gru_final(const char* __restrict__ ws,
                          const float* __restrict__ gamma, const float* __restrict__ beta,
                          const float* __restrict__ fcw, const float* __restrict__ fcb,
                          float* __restrict__ out)
{
    __shared__ float summ[HH];
    const int b = blockIdx.x, c = threadIdx.x;
    const float* bnsum = (const float*)(ws + OFF_BNSUM);
    const float* bnsq  = (const float*)(ws + OFF_BNSQ);
    const short* h2seq = (const short*)(ws + OFF_H2SEQ);

    const float inv = 1.f / (float)(BB * TT);
    float mean = bnsum[c] * inv;
    float var  = bnsq[c] * inv - mean * mean;
    float scale = rsqrtf(var + EPSV) * gamma[c];
    float shift = beta[c] - mean * scale;

    const short* p = h2seq + (size_t)b*TT*HH + c;
    float acc = 0.f;
    #pragma unroll 4
    for (int t = 0; t < TT; ++t) {
        float v = bf2f(p[t*HH]) * scale + shift;
        v = fminf(fmaxf(v, -2.f), 2.f);
        acc += v;
    }
    summ[c] = acc * (1.f / TT);
    __syncthreads();
    if (c < OUTD) {
        float d = fcb[c];
        const float* wr = fcw + c*HH;
        #pragma unroll 8
        for (int h = 0; h < HH; ++h) d += wr[h] * summ[h];
        out[b*OUTD + c] = d;
    }
}

extern "C" void kernel_launch(void* const* d_in, const int* in_sizes, int n_in,
                              void* d_out, int out_size, void* d_ws, size_t ws_size,
                              hipStream_t stream)
{
    const float* x    = (const float*)d_in[0];
    const float* wih1 = (const float*)d_in[1];
    const float* whh1 = (const float*)d_in[2];
    const float* bih1 = (const float*)d_in[3];
    const float* bhh1 = (const float*)d_in[4];
    const float* wih2 = (const float*)d_in[5];
    const float* whh2 = (const float*)d_in[6];
    const float* bih2 = (const float*)d_in[7];
    const float* bhh2 = (const float*)d_in[8];
    const float* gamma= (const float*)d_in[9];
    const float* beta = (const float*)d_in[10];
    const float* fcw  = (const float*)d_in[11];
    const float* fcb  = (const float*)d_in[12];
    char* ws = (char*)d_ws;

    // progress counters + BN accumulators must start at 0
    (void)hipMemsetAsync(ws, 0, OFF_ZERO_END, stream);

    const int nx = BB*TT*II;
    hipLaunchKernelGGL(cvt_x, dim3(nx/4/256), dim3(256), 0, stream,
                       x, (short*)(ws + OFF_XBF), nx);

    // 16 clusters x 4 stages = 64 co-resident WGs (one per CU)
    hipLaunchKernelGGL(gru_pipe, dim3(NCL*4), dim3(512), 0, stream,
                       (const short*)(ws + OFF_XBF),
                       wih1, whh1, bih1, bhh1, wih2, whh2, bih2, bhh2, ws);

    hipLaunchKernelGGL(gru_final, dim3(BB), dim3(HH), 0, stream,
                       (const char*)ws, gamma, beta, fcw, fcb, (float*)d_out);
}